// Round 18
// baseline (2346.162 us; speedup 1.0000x reference)
//
#include <hip/hip_runtime.h>
#include <stdint.h>
#include <math.h>

#define B_DIM 256
#define P_DIM 4096
#define L_DIM 8192
#define NSTEPS 50
#define STEP 0.1f
#define LAM 0.1f
#define FP8_ITERS 42          // scan steps in fp8; last 6 in exact bf16 (error-decay tail)
#define GSCALE 64.0f
#define ASCALE 16.0f
#define INV_SCALE (1.0f / (64.0f * 16.0f))

typedef __attribute__((ext_vector_type(8))) short bf16x8;
typedef __attribute__((ext_vector_type(4))) float f32x4;
typedef __attribute__((ext_vector_type(4))) int i32x4;
typedef __attribute__((ext_vector_type(8))) int i32x8;

__device__ __forceinline__ unsigned short f2bf(float f) {
    union { float f; uint32_t u; } x; x.f = f;
    uint32_t r = (x.u + 0x7FFF + ((x.u >> 16) & 1)) >> 16;
    return (unsigned short)r;
}
__device__ __forceinline__ float bf2f(unsigned short h) {
    union { uint32_t u; float f; } x; x.u = (uint32_t)h << 16; return x.f;
}

// k-shuffled fp8 layout (128-elem chunks): byte position of element k (r = k & 127):
//   dst = (k & ~127) + ((r>>6)&1)*64 + ((r>>3)&3)*16 + ((r>>5)&1)*8 + (k&7)
// Slot c (16B) holds a kk-pair; slots {g, 4+g} hold lane-group g's K=128 fragment.
// A and B share the packing -> hw (lane,byte)->k map is a common permutation -> exact dot.

// ---------------- cast x (f32 -> bf16), vectorized ----------------
__global__ void cast_x_kernel(const float* __restrict__ in, unsigned short* __restrict__ out, int n) {
    int i = (blockIdx.x * blockDim.x + threadIdx.x) * 4;
    if (i < n) {
        float4 v = *(const float4*)&in[i];
        ushort4 o;
        o.x = f2bf(v.x); o.y = f2bf(v.y); o.z = f2bf(v.z); o.w = f2bf(v.w);
        *(ushort4*)&out[i] = o;
    }
}

// ------------- cast + transpose w: w[P][L] f32 -> w_bf[P][L], wT_bf[L][P] -------------
__global__ void cast_transpose_w(const float* __restrict__ w,
                                 unsigned short* __restrict__ w_bf,
                                 unsigned short* __restrict__ wT_bf) {
    __shared__ float tile[32][33];
    int c0 = blockIdx.x * 32;
    int r0 = blockIdx.y * 32;
    int tx = threadIdx.x, ty = threadIdx.y;  // 32 x 8
#pragma unroll
    for (int i = ty; i < 32; i += 8) {
        float v = w[(size_t)(r0 + i) * L_DIM + c0 + tx];
        tile[i][tx] = v;
        w_bf[(size_t)(r0 + i) * L_DIM + c0 + tx] = f2bf(v);
    }
    __syncthreads();
#pragma unroll
    for (int i = ty; i < 32; i += 8) {
        wT_bf[(size_t)(c0 + i) * P_DIM + r0 + tx] = f2bf(tile[tx][i]);
    }
}

// ---------------- quantize G (bf16 -> fp8 e4m3 x64, k-shuffled) ----------------
__global__ void quantize_G(const unsigned short* __restrict__ G, unsigned char* __restrict__ Gf) {
    size_t i = ((size_t)blockIdx.x * 256 + threadIdx.x) * 8;
    bf16x8 v = *(const bf16x8*)&G[i];
    float f[8];
#pragma unroll
    for (int j = 0; j < 8; ++j) f[j] = bf2f((unsigned short)v[j]) * GSCALE;
    int q0 = __builtin_amdgcn_cvt_pk_fp8_f32(f[0], f[1], 0, false);
    q0 = __builtin_amdgcn_cvt_pk_fp8_f32(f[2], f[3], q0, true);
    int q1 = __builtin_amdgcn_cvt_pk_fp8_f32(f[4], f[5], 0, false);
    q1 = __builtin_amdgcn_cvt_pk_fp8_f32(f[6], f[7], q1, true);
    const int r = (int)(i & 127);
    size_t dst = (i & ~(size_t)127) + (size_t)((((r >> 6) & 1) << 6) + (((r >> 3) & 3) << 4) + (((r >> 5) & 1) << 3));
    *(int2*)(Gf + dst) = make_int2(q0, q1);
}

// ======================= gemm_pipe: NBUF=4 counted-vmcnt (b / recon) =======================
template <int BM, int BN, int BK, int WMC, int WNC, int EPI, int MM, int NN, int KK, int MAP>
__global__ __launch_bounds__(WMC * WNC * 64)
void gemm_pipe(const unsigned short* __restrict__ A,
               const unsigned short* __restrict__ Bt,
               float* __restrict__ Cf,
               float* __restrict__ uvec,
               unsigned short* __restrict__ aout,
               unsigned char* __restrict__ afp8) {
    constexpr int NWAVES = WMC * WNC;
    constexpr int WM = BM / WMC, WN = BN / WNC;
    constexpr int MF = WM / 16, NF = WN / 16;
    constexpr int ACH = BM / (8 * NWAVES);
    constexpr int BCH = BN / (8 * NWAVES);
    constexpr int LPS = ACH + BCH;
    constexpr int NT = KK / BK;
    static_assert(BK == 64, "swizzle hardcoded for BK=64");
    static_assert(ACH * 8 * NWAVES == BM && BCH * 8 * NWAVES == BN, "stage geometry");
    static_assert(NT % 4 == 0 && NT >= 8, "pipeline geometry");

    __shared__ __align__(16) unsigned short As[4][BM * BK];
    __shared__ __align__(16) unsigned short Bs[4][BN * BK];

    const int tid = threadIdx.x;
    const int w = tid >> 6;
    const int l = tid & 63;
    const int wr = w / WNC, wc = w % WNC;

    const int id = blockIdx.x;
    int bx, by;
    if constexpr (MAP == 0) {
        constexpr int PPX = (NN / BN) / 8;
        static_assert(MM / BM == 4 && (NN / BN) % 8 == 0, "panel map geometry");
        bx = (id & 7) * PPX + ((id >> 3) >> 2);
        by = (id >> 3) & 3;
    } else {
        constexpr int GY = MM / BM;
        by = id % GY;
        bx = id / GY;
    }
    const int row0 = by * BM;
    const int col0 = bx * BN;

    const int lrow = l >> 3;
    const int lcol = (((l & 7) ^ lrow) * 8);

    const unsigned short* gA = A + (size_t)(row0 + lrow) * KK + lcol;
    const unsigned short* gB = Bt + (size_t)(col0 + lrow) * KK + lcol;

    auto stage = [&](int buf, int k0) {
#pragma unroll
        for (int i = 0; i < ACH; ++i) {
            const int chunk = i * NWAVES + w;
            __builtin_amdgcn_global_load_lds(
                (const __attribute__((address_space(1))) void*)(gA + (size_t)chunk * 8 * KK + k0),
                (__attribute__((address_space(3))) void*)(&As[buf][chunk * 512]), 16, 0, 0);
        }
#pragma unroll
        for (int i = 0; i < BCH; ++i) {
            const int chunk = i * NWAVES + w;
            __builtin_amdgcn_global_load_lds(
                (const __attribute__((address_space(1))) void*)(gB + (size_t)chunk * 8 * KK + k0),
                (__attribute__((address_space(3))) void*)(&Bs[buf][chunk * 512]), 16, 0, 0);
        }
    };

    f32x4 acc[MF][NF] = {};

    auto compute = [&](int buf) {
#pragma unroll
        for (int kk = 0; kk < BK; kk += 32) {
            const int kslot = (kk >> 3) + (l >> 4);
            bf16x8 af[MF], bfr[NF];
#pragma unroll
            for (int mf = 0; mf < MF; ++mf) {
                const int arow = wr * WM + mf * 16 + (l & 15);
                af[mf] = *(const bf16x8*)&As[buf][arow * BK + ((kslot ^ (arow & 7)) << 3)];
            }
#pragma unroll
            for (int nf = 0; nf < NF; ++nf) {
                const int brow = wc * WN + nf * 16 + (l & 15);
                bfr[nf] = *(const bf16x8*)&Bs[buf][brow * BK + ((kslot ^ (brow & 7)) << 3)];
            }
#pragma unroll
            for (int mf = 0; mf < MF; ++mf)
#pragma unroll
                for (int nf = 0; nf < NF; ++nf)
                    acc[mf][nf] = __builtin_amdgcn_mfma_f32_16x16x32_bf16(
                        af[mf], bfr[nf], acc[mf][nf], 0, 0, 0);
        }
    };

#define PH(BUF, TT, WAITN, DOSTG)                                            \
    asm volatile("s_waitcnt vmcnt(%0)" ::"i"(WAITN) : "memory");             \
    __builtin_amdgcn_s_barrier();                                            \
    asm volatile("" ::: "memory");                                           \
    if (DOSTG) stage((BUF + 3) & 3, ((TT) + 3) * BK);                        \
    compute(BUF);

    stage(0, 0);
    stage(1, BK);
    stage(2, 2 * BK);
#pragma unroll 1
    for (int t = 0; t < NT - 4; t += 4) {
        PH(0, t + 0, 2 * LPS, true)
        PH(1, t + 1, 2 * LPS, true)
        PH(2, t + 2, 2 * LPS, true)
        PH(3, t + 3, 2 * LPS, true)
    }
    PH(0, NT - 4, 2 * LPS, true)
    PH(1, NT - 3, 2 * LPS, false)
    PH(2, NT - 2, LPS, false)
    PH(3, NT - 1, 0, false)
#undef PH

    const int er = (l >> 4) * 4;
    const int ec = l & 15;
#pragma unroll
    for (int mf = 0; mf < MF; ++mf) {
#pragma unroll
        for (int nf = 0; nf < NF; ++nf) {
#pragma unroll
            for (int j = 0; j < 4; ++j) {
                int gr = row0 + wr * WM + mf * 16 + er + j;
                int gc = col0 + wc * WN + nf * 16 + ec;
                size_t idx = (size_t)gr * NN + gc;
                float v = acc[mf][nf][j];
                if constexpr (EPI == 1) {
                    Cf[idx] = v;
                    float u0 = STEP * v;
                    uvec[idx] = u0;
                    float a = (u0 > LAM) ? (u0 - LAM) : 0.0f;
                    aout[idx] = f2bf(a);
                    float a16 = a * ASCALE;
                    int q = __builtin_amdgcn_cvt_pk_fp8_f32(a16, a16, 0, false);
                    const int r = gc & 127;
                    size_t fd = (size_t)gr * L_DIM + (size_t)(gc & ~127) +
                                (size_t)((((r >> 6) & 1) << 6) + (((r >> 3) & 3) << 4) + (((r >> 5) & 1) << 3) + (r & 7));
                    afp8[fd] = (unsigned char)(q & 0xff);
                } else {
                    Cf[idx] = v;
                }
            }
        }
    }
}

// ======================= gemm_gram_sym v1: 256^2 tiles, 8 waves, 528 blocks (r10-proven) ========
__global__ __launch_bounds__(512, 2)
void gemm_gram_sym(const unsigned short* __restrict__ A,
                   unsigned short* __restrict__ G) {
    constexpr int BM = 256, BN = 256, BK = 64;
    constexpr int WMC = 2, WNC = 4, NWAVES = 8;
    constexpr int WM = 128, WN = 64, MF = 8, NF = 4;
    constexpr int ACH = 4, BCH = 4, LPS = 8;
    constexpr int NT = P_DIM / BK;   // 64

    __shared__ __align__(16) unsigned short sh[4 * 256 * 64];  // 128 KB
#define ASB(buf) (sh + (buf) * (256 * 64))
#define BSB(buf) (sh + (2 + (buf)) * (256 * 64))

    const int tid = threadIdx.x;
    const int w = tid >> 6;
    const int l = tid & 63;
    const int wr = w / WNC, wc = w % WNC;

    const int id = blockIdx.x;
    const int i = (int)((65.0f - sqrtf(4225.0f - 8.0f * (float)id)) * 0.5f);
    const int cum = i * (65 - i) / 2;
    const int j = i + (id - cum);
    const int by = i, bx = j;
    const int row0 = by * BM;
    const int col0 = bx * BN;

    const int lrow = l >> 3;
    const int lcol = (((l & 7) ^ lrow) * 8);

    const unsigned short* gA = A + (size_t)(row0 + lrow) * P_DIM + lcol;
    const unsigned short* gB = A + (size_t)(col0 + lrow) * P_DIM + lcol;

    auto stage = [&](int buf, int t) {
        const int k0 = t * BK;
#pragma unroll
        for (int c = 0; c < ACH; ++c) {
            const int chunk = c * NWAVES + w;
            __builtin_amdgcn_global_load_lds(
                (const __attribute__((address_space(1))) void*)(gA + (size_t)chunk * 8 * P_DIM + k0),
                (__attribute__((address_space(3))) void*)(ASB(buf) + chunk * 512), 16, 0, 0);
        }
#pragma unroll
        for (int c = 0; c < BCH; ++c) {
            const int chunk = c * NWAVES + w;
            __builtin_amdgcn_global_load_lds(
                (const __attribute__((address_space(1))) void*)(gB + (size_t)chunk * 8 * P_DIM + k0),
                (__attribute__((address_space(3))) void*)(BSB(buf) + chunk * 512), 16, 0, 0);
        }
    };

    f32x4 acc[MF][NF] = {};

    auto compute = [&](int buf) {
#pragma unroll
        for (int kk = 0; kk < BK; kk += 32) {
            const int kslot = (kk >> 3) + (l >> 4);
            bf16x8 af[MF], bfr[NF];
#pragma unroll
            for (int mf = 0; mf < MF; ++mf) {
                const int arow = wr * WM + mf * 16 + (l & 15);
                af[mf] = *(const bf16x8*)&ASB(buf)[arow * BK + ((kslot ^ (arow & 7)) << 3)];
            }
#pragma unroll
            for (int nf = 0; nf < NF; ++nf) {
                const int brow = wc * WN + nf * 16 + (l & 15);
                bfr[nf] = *(const bf16x8*)&BSB(buf)[brow * BK + ((kslot ^ (brow & 7)) << 3)];
            }
#pragma unroll
            for (int mf = 0; mf < MF; ++mf)
#pragma unroll
                for (int nf = 0; nf < NF; ++nf)
                    acc[mf][nf] = __builtin_amdgcn_mfma_f32_16x16x32_bf16(
                        af[mf], bfr[nf], acc[mf][nf], 0, 0, 0);
        }
    };

#define PH2(BUF, WAITN, DOSTG, TT)                                           \
    asm volatile("s_waitcnt vmcnt(%0)" ::"i"(WAITN) : "memory");             \
    __builtin_amdgcn_s_barrier();                                            \
    asm volatile("" ::: "memory");                                           \
    compute(BUF);                                                            \
    __builtin_amdgcn_s_barrier();                                            \
    asm volatile("" ::: "memory");                                           \
    if (DOSTG) stage(BUF, (TT) + 2);

    stage(0, 0);
    stage(1, 1);
#pragma unroll 1
    for (int t = 0; t < NT - 2; t += 2) {
        PH2(0, LPS, true, t)
        PH2(1, LPS, true, t + 1)
    }
    PH2(0, LPS, false, 0)
    PH2(1, 0, false, 0)
#undef PH2

    const int er = (l >> 4) * 4;
    const int ec = l & 15;

#pragma unroll
    for (int mf = 0; mf < MF; ++mf)
#pragma unroll
        for (int nf = 0; nf < NF; ++nf)
#pragma unroll
            for (int jj = 0; jj < 4; ++jj) {
                int gr = row0 + wr * WM + mf * 16 + er + jj;
                int gc = col0 + wc * WN + nf * 16 + ec;
                float v = acc[mf][nf][jj];
                if (gr == gc) v -= 1.0f;
                G[(size_t)gr * L_DIM + gc] = f2bf(v);
            }

    if (by != bx) {
        unsigned short* T = sh;
#pragma unroll 1
        for (int p = 0; p < 2; ++p) {
            __syncthreads();
            if ((wc >> 1) == p) {
#pragma unroll
                for (int mf = 0; mf < MF; ++mf)
#pragma unroll
                    for (int nf = 0; nf < NF; ++nf)
#pragma unroll
                        for (int jj = 0; jj < 4; ++jj) {
                            const int gr_l = wr * WM + mf * 16 + er + jj;
                            const int gc_l = (wc & 1) * 64 + nf * 16 + ec;
                            T[gc_l * 256 + (gr_l ^ ((gc_l & 7) << 2))] = f2bf(acc[mf][nf][jj]);
                        }
            }
            __syncthreads();
            const int rr = tid >> 6;
            const int cc = (tid & 63) * 4;
#pragma unroll
            for (int s = 0; s < 16; ++s) {
                const int r = s * 8 + rr;
                uint2 val = *(const uint2*)&T[r * 256 + (cc ^ ((r & 7) << 2))];
                *(uint2*)&G[(size_t)(col0 + p * 128 + r) * L_DIM + row0 + cc] = val;
            }
        }
    }
#undef ASB
#undef BSB
}

// ======================= gemm2: bf16 NBUF=2 two-barrier counted-vmcnt (bf16-tail iters) =====
template <int BM, int BN, int WMC, int WNC, int EPI, int KROW, int KLOOP, int MAP>
__global__ __launch_bounds__(WMC * WNC * 64, 2)
void gemm2(const unsigned short* __restrict__ A,
           const unsigned short* __restrict__ Bt,
           unsigned short* __restrict__ Obf) {
    constexpr int NWAVES = WMC * WNC;
    constexpr int WM = BM / WMC, WN = BN / WNC;
    constexpr int MF = WM / 16, NF = WN / 16;
    constexpr int ACH = BM / (8 * NWAVES);
    constexpr int BCH = BN / (8 * NWAVES);
    constexpr int LPS = ACH + BCH;
    constexpr int BK = 64;
    constexpr int NT = KLOOP / BK;
    static_assert(ACH * 8 * NWAVES == BM && BCH * 8 * NWAVES == BN, "stage geometry");
    static_assert(NT % 2 == 0 && NT >= 4, "pipeline geometry");

    __shared__ __align__(16) unsigned short As[2][BM * BK];
    __shared__ __align__(16) unsigned short Bs[2][BN * BK];

    const int tid = threadIdx.x;
    const int w = tid >> 6;
    const int l = tid & 63;
    const int wr = w / WNC, wc = w % WNC;

    const int id = blockIdx.x;
    int bx, by, koff;
    size_t o_off;
    {
        const int xcd = id & 7;
        by = (id >> 3) & 1;
        const int pp = id >> 4;
        const int slice = pp & 3;
        bx = xcd * 4 + (pp >> 2);
        koff = slice * KLOOP;
        o_off = (size_t)slice * B_DIM * L_DIM;
    }
    const int row0 = by * BM;
    const int col0 = bx * BN;

    const int lrow = l >> 3;
    const int lcol = (((l & 7) ^ lrow) * 8);

    const unsigned short* gA = A + (size_t)(row0 + lrow) * KROW + koff + lcol;
    const unsigned short* gB = Bt + (size_t)(col0 + lrow) * KROW + koff + lcol;

    auto stage = [&](int buf, int t) {
        const int k0 = t * BK;
#pragma unroll
        for (int i = 0; i < ACH; ++i) {
            const int chunk = i * NWAVES + w;
            __builtin_amdgcn_global_load_lds(
                (const __attribute__((address_space(1))) void*)(gA + (size_t)chunk * 8 * KROW + k0),
                (__attribute__((address_space(3))) void*)(&As[buf][chunk * 512]), 16, 0, 0);
        }
#pragma unroll
        for (int i = 0; i < BCH; ++i) {
            const int chunk = i * NWAVES + w;
            __builtin_amdgcn_global_load_lds(
                (const __attribute__((address_space(1))) void*)(gB + (size_t)chunk * 8 * KROW + k0),
                (__attribute__((address_space(3))) void*)(&Bs[buf][chunk * 512]), 16, 0, 0);
        }
    };

    f32x4 acc[MF][NF] = {};

    auto compute = [&](int buf) {
#pragma unroll
        for (int kk = 0; kk < BK; kk += 32) {
            const int kslot = (kk >> 3) + (l >> 4);
            bf16x8 af[MF], bfr[NF];
#pragma unroll
            for (int mf = 0; mf < MF; ++mf) {
                const int arow = wr * WM + mf * 16 + (l & 15);
                af[mf] = *(const bf16x8*)&As[buf][arow * BK + ((kslot ^ (arow & 7)) << 3)];
            }
#pragma unroll
            for (int nf = 0; nf < NF; ++nf) {
                const int brow = wc * WN + nf * 16 + (l & 15);
                bfr[nf] = *(const bf16x8*)&Bs[buf][brow * BK + ((kslot ^ (brow & 7)) << 3)];
            }
#pragma unroll
            for (int mf = 0; mf < MF; ++mf)
#pragma unroll
                for (int nf = 0; nf < NF; ++nf)
                    acc[mf][nf] = __builtin_amdgcn_mfma_f32_16x16x32_bf16(
                        af[mf], bfr[nf], acc[mf][nf], 0, 0, 0);
        }
    };

#define PH2(BUF, WAITN, DOSTG, TT)                                           \
    asm volatile("s_waitcnt vmcnt(%0)" ::"i"(WAITN) : "memory");             \
    __builtin_amdgcn_s_barrier();                                            \
    asm volatile("" ::: "memory");                                           \
    compute(BUF);                                                            \
    __builtin_amdgcn_s_barrier();                                            \
    asm volatile("" ::: "memory");                                           \
    if (DOSTG) stage(BUF, (TT) + 2);

    stage(0, 0);
    stage(1, 1);
#pragma unroll 1
    for (int t = 0; t < NT - 2; t += 2) {
        PH2(0, LPS, true, t)
        PH2(1, LPS, true, t + 1)
    }
    PH2(0, LPS, false, 0)
    PH2(1, 0, false, 0)
#undef PH2

    const int er = (l >> 4) * 4;
    const int ec = l & 15;
#pragma unroll
    for (int mf = 0; mf < MF; ++mf)
#pragma unroll
        for (int nf = 0; nf < NF; ++nf)
#pragma unroll
            for (int j = 0; j < 4; ++j) {
                int gr = row0 + wr * WM + mf * 16 + er + j;
                int gc = col0 + wc * WN + nf * 16 + ec;
                Obf[o_off + (size_t)gr * L_DIM + gc] = f2bf(acc[mf][nf][j]);
            }
}

// ======================= gemm_fp8 v2: MX K=128, BM=256, WM=128/WN=64, split-K=8 ================
// r18: all 256 rows in one block (BM=256), 8 waves 2x4 -> WM=128/WN=64 (LDS-read factor
// 0.0234 vs 0.0312) and NT=8 phases (halved fixed per-phase overhead). Grid 256 = 1 blk/CU.
// LDS 2x(32+32)=128KB. MINB=1 so the allocator isn't VGPR-capped (~acc128+frag regs).
__global__ __launch_bounds__(512, 1)
void gemm_fp8(const unsigned char* __restrict__ A,
              const unsigned char* __restrict__ Bt,
              unsigned short* __restrict__ Obf) {
    constexpr int NWAVES = 8;
    constexpr int BM = 256, BN = 256;
    constexpr int WMC = 2, WNC = 4;
    constexpr int WM = 128, WN = 64, MF = 8, NF = 4;
    constexpr int BKB = 128;
    constexpr int ACH = BM / (8 * NWAVES);   // 4
    constexpr int BCH = BN / (8 * NWAVES);   // 4
    constexpr int LPS = ACH + BCH;           // 8
    constexpr int KLOOP = 1024;              // K per slice (split-K=8)
    constexpr int NT = KLOOP / BKB;          // 8
    constexpr int KKB = L_DIM;

    __shared__ __align__(16) unsigned char As[2][BM * BKB];   // 64 KB
    __shared__ __align__(16) unsigned char Bs[2][BN * BKB];   // 64 KB

    const int tid = threadIdx.x;
    const int w = tid >> 6;
    const int l = tid & 63;
    const int wr = w / WNC, wc = w % WNC;

    // 256 blocks: xcd = id&7; q = id>>3 (0..31): slice = q&7, bx = xcd*4 + (q>>3)
    const int id = blockIdx.x;
    const int xcd = id & 7;
    const int q = id >> 3;
    const int slice = q & 7;
    const int bx = xcd * 4 + (q >> 3);
    const int col0 = bx * BN;
    const int koff = slice * KLOOP;

    const int lrow = l >> 3;
    const int lcol = (((l & 7) ^ lrow) << 4);

    const unsigned char* gA = A + (size_t)lrow * KKB + koff + lcol;          // row0 = 0
    const unsigned char* gB = Bt + (size_t)(col0 + lrow) * KKB + koff + lcol;

    auto stage = [&](int buf, int t) {
        const int k0 = t * BKB;
#pragma unroll
        for (int i = 0; i < ACH; ++i) {
            const int chunk = i * NWAVES + w;
            __builtin_amdgcn_global_load_lds(
                (const __attribute__((address_space(1))) void*)(gA + (size_t)chunk * 8 * KKB + k0),
                (__attribute__((address_space(3))) void*)(&As[buf][chunk * 1024]), 16, 0, 0);
        }
#pragma unroll
        for (int i = 0; i < BCH; ++i) {
            const int chunk = i * NWAVES + w;
            __builtin_amdgcn_global_load_lds(
                (const __attribute__((address_space(1))) void*)(gB + (size_t)chunk * 8 * KKB + k0),
                (__attribute__((address_space(3))) void*)(&Bs[buf][chunk * 1024]), 16, 0, 0);
        }
    };

    f32x4 acc[MF][NF] = {};

    auto compute = [&](int buf) {
        const int g = l >> 4;
        i32x8 b8[NF];
#pragma unroll
        for (int nf = 0; nf < NF; ++nf) {
            const int brow = wc * WN + nf * 16 + (l & 15);
            i32x4 lo = *(const i32x4*)&Bs[buf][brow * BKB + (((g) ^ (brow & 7)) << 4)];
            i32x4 hi = *(const i32x4*)&Bs[buf][brow * BKB + (((4 + g) ^ (brow & 7)) << 4)];
            b8[nf] = i32x8{lo[0], lo[1], lo[2], lo[3], hi[0], hi[1], hi[2], hi[3]};
        }
#pragma unroll
        for (int mf = 0; mf < MF; ++mf) {
            const int arow = wr * WM + mf * 16 + (l & 15);
            i32x4 lo = *(const i32x4*)&As[buf][arow * BKB + (((g) ^ (arow & 7)) << 4)];
            i32x4 hi = *(const i32x4*)&As[buf][arow * BKB + (((4 + g) ^ (arow & 7)) << 4)];
            i32x8 a8 = i32x8{lo[0], lo[1], lo[2], lo[3], hi[0], hi[1], hi[2], hi[3]};
#pragma unroll
            for (int nf = 0; nf < NF; ++nf)
                acc[mf][nf] = __builtin_amdgcn_mfma_scale_f32_16x16x128_f8f6f4(
                    a8, b8[nf], acc[mf][nf],
                    0, 0,        // cbsz, blgp: fp8 e4m3 both
                    0, 127,      // scale_a = e8m0(2^0) = 1.0
                    0, 127);     // scale_b = 1.0
        }
    };

#define PH2(BUF, WAITN, DOSTG, TT)                                           \
    asm volatile("s_waitcnt vmcnt(%0)" ::"i"(WAITN) : "memory");             \
    __builtin_amdgcn_s_barrier();                                            \
    asm volatile("" ::: "memory");                                           \
    compute(BUF);                                                            \
    __builtin_amdgcn_s_barrier();                                            \
    asm volatile("" ::: "memory");                                           \
    if (DOSTG) stage(BUF, (TT) + 2);

    stage(0, 0);
    stage(1, 1);
#pragma unroll 1
    for (int t = 0; t < NT - 2; t += 2) {
        PH2(0, LPS, true, t)
        PH2(1, LPS, true, t + 1)
    }
    PH2(0, LPS, false, 0)
    PH2(1, 0, false, 0)
#undef PH2

    const int er = (l >> 4) * 4;
    const int ec = l & 15;
    const size_t o_off = (size_t)slice * B_DIM * L_DIM;
#pragma unroll
    for (int mf = 0; mf < MF; ++mf)
#pragma unroll
        for (int nf = 0; nf < NF; ++nf)
#pragma unroll
            for (int j = 0; j < 4; ++j) {
                int gr = wr * WM + mf * 16 + er + j;
                int gc = col0 + wc * WN + nf * 16 + ec;
                Obf[o_off + (size_t)gr * L_DIM + gc] = f2bf(acc[mf][nf][j] * INV_SCALE);
            }
}

// ---------------- reduce (4-slice, bf16-tail path) ----------------
__global__ void reduce_iter4(const unsigned short* __restrict__ P,
                             const float* __restrict__ bv,
                             float* __restrict__ uv,
                             unsigned short* __restrict__ an,
                             unsigned char* __restrict__ anf) {
    constexpr size_t SL = (size_t)B_DIM * L_DIM;
    size_t i = ((size_t)blockIdx.x * 256 + threadIdx.x) * 8;
    float s[8] = {};
#pragma unroll
    for (int sl = 0; sl < 4; ++sl) {
        ushort4 p0 = *(const ushort4*)&P[sl * SL + i];
        ushort4 p1 = *(const ushort4*)&P[sl * SL + i + 4];
        s[0] += bf2f(p0.x); s[1] += bf2f(p0.y); s[2] += bf2f(p0.z); s[3] += bf2f(p0.w);
        s[4] += bf2f(p1.x); s[5] += bf2f(p1.y); s[6] += bf2f(p1.z); s[7] += bf2f(p1.w);
    }
    float4 b0 = *(const float4*)&bv[i];
    float4 b1 = *(const float4*)&bv[i + 4];
    float4 u0 = *(const float4*)&uv[i];
    float4 u1 = *(const float4*)&uv[i + 4];
    float un[8];
    un[0] = 0.9f * u0.x + STEP * b0.x - STEP * s[0];
    un[1] = 0.9f * u0.y + STEP * b0.y - STEP * s[1];
    un[2] = 0.9f * u0.z + STEP * b0.z - STEP * s[2];
    un[3] = 0.9f * u0.w + STEP * b0.w - STEP * s[3];
    un[4] = 0.9f * u1.x + STEP * b1.x - STEP * s[4];
    un[5] = 0.9f * u1.y + STEP * b1.y - STEP * s[5];
    un[6] = 0.9f * u1.z + STEP * b1.z - STEP * s[6];
    un[7] = 0.9f * u1.w + STEP * b1.w - STEP * s[7];
    *(float4*)&uv[i] = make_float4(un[0], un[1], un[2], un[3]);
    *(float4*)&uv[i + 4] = make_float4(un[4], un[5], un[6], un[7]);
    float a[8];
#pragma unroll
    for (int j = 0; j < 8; ++j) a[j] = (un[j] > LAM) ? (un[j] - LAM) : 0.0f;
    ushort4 o0, o1;
    o0.x = f2bf(a[0]); o0.y = f2bf(a[1]); o0.z = f2bf(a[2]); o0.w = f2bf(a[3]);
    o1.x = f2bf(a[4]); o1.y = f2bf(a[5]); o1.z = f2bf(a[6]); o1.w = f2bf(a[7]);
    *(ushort4*)&an[i] = o0;
    *(ushort4*)&an[i + 4] = o1;
    int q0 = __builtin_amdgcn_cvt_pk_fp8_f32(a[0] * ASCALE, a[1] * ASCALE, 0, false);
    q0 = __builtin_amdgcn_cvt_pk_fp8_f32(a[2] * ASCALE, a[3] * ASCALE, q0, true);
    int q1 = __builtin_amdgcn_cvt_pk_fp8_f32(a[4] * ASCALE, a[5] * ASCALE, 0, false);
    q1 = __builtin_amdgcn_cvt_pk_fp8_f32(a[6] * ASCALE, a[7] * ASCALE, q1, true);
    const int r = (int)(i & 127);
    size_t dst = (i & ~(size_t)127) + (size_t)((((r >> 6) & 1) << 6) + (((r >> 3) & 3) << 4) + (((r >> 5) & 1) << 3));
    *(int2*)(anf + dst) = make_int2(q0, q1);
}

// ---------------- reduce (8-slice, fp8 split-K=8 path) ----------------
__global__ void reduce_iter8(const unsigned short* __restrict__ P,
                             const float* __restrict__ bv,
                             float* __restrict__ uv,
                             unsigned short* __restrict__ an,
                             unsigned char* __restrict__ anf) {
    constexpr size_t SL = (size_t)B_DIM * L_DIM;
    size_t i = ((size_t)blockIdx.x * 256 + threadIdx.x) * 8;
    float s[8] = {};
#pragma unroll
    for (int sl = 0; sl < 8; ++sl) {           // fixed slice order 0..7 (determinism)
        ushort4 p0 = *(const ushort4*)&P[sl * SL + i];
        ushort4 p1 = *(const ushort4*)&P[sl * SL + i + 4];
        s[0] += bf2f(p0.x); s[1] += bf2f(p0.y); s[2] += bf2f(p0.z); s[3] += bf2f(p0.w);
        s[4] += bf2f(p1.x); s[5] += bf2f(p1.y); s[6] += bf2f(p1.z); s[7] += bf2f(p1.w);
    }
    float4 b0 = *(const float4*)&bv[i];
    float4 b1 = *(const float4*)&bv[i + 4];
    float4 u0 = *(const float4*)&uv[i];
    float4 u1 = *(const float4*)&uv[i + 4];
    float un[8];
    un[0] = 0.9f * u0.x + STEP * b0.x - STEP * s[0];
    un[1] = 0.9f * u0.y + STEP * b0.y - STEP * s[1];
    un[2] = 0.9f * u0.z + STEP * b0.z - STEP * s[2];
    un[3] = 0.9f * u0.w + STEP * b0.w - STEP * s[3];
    un[4] = 0.9f * u1.x + STEP * b1.x - STEP * s[4];
    un[5] = 0.9f * u1.y + STEP * b1.y - STEP * s[5];
    un[6] = 0.9f * u1.z + STEP * b1.z - STEP * s[6];
    un[7] = 0.9f * u1.w + STEP * b1.w - STEP * s[7];
    *(float4*)&uv[i] = make_float4(un[0], un[1], un[2], un[3]);
    *(float4*)&uv[i + 4] = make_float4(un[4], un[5], un[6], un[7]);
    float a[8];
#pragma unroll
    for (int j = 0; j < 8; ++j) a[j] = (un[j] > LAM) ? (un[j] - LAM) : 0.0f;
    ushort4 o0, o1;
    o0.x = f2bf(a[0]); o0.y = f2bf(a[1]); o0.z = f2bf(a[2]); o0.w = f2bf(a[3]);
    o1.x = f2bf(a[4]); o1.y = f2bf(a[5]); o1.z = f2bf(a[6]); o1.w = f2bf(a[7]);
    *(ushort4*)&an[i] = o0;
    *(ushort4*)&an[i + 4] = o1;
    int q0 = __builtin_amdgcn_cvt_pk_fp8_f32(a[0] * ASCALE, a[1] * ASCALE, 0, false);
    q0 = __builtin_amdgcn_cvt_pk_fp8_f32(a[2] * ASCALE, a[3] * ASCALE, q0, true);
    int q1 = __builtin_amdgcn_cvt_pk_fp8_f32(a[4] * ASCALE, a[5] * ASCALE, 0, false);
    q1 = __builtin_amdgcn_cvt_pk_fp8_f32(a[6] * ASCALE, a[7] * ASCALE, q1, true);
    const int r = (int)(i & 127);
    size_t dst = (i & ~(size_t)127) + (size_t)((((r >> 6) & 1) << 6) + (((r >> 3) & 3) << 4) + (((r >> 5) & 1) << 3));
    *(int2*)(anf + dst) = make_int2(q0, q1);
}

extern "C" void kernel_launch(void* const* d_in, const int* in_sizes, int n_in,
                              void* d_out, int out_size, void* d_ws, size_t ws_size,
                              hipStream_t stream) {
    (void)in_sizes; (void)n_in; (void)out_size; (void)ws_size;
    const float* x = (const float*)d_in[0];
    const float* w = (const float*)d_in[1];
    float* out = (float*)d_out;

    char* ws = (char*)d_ws;
    unsigned short* wT  = (unsigned short*)ws;                    // [L][P] 64MB; dead after b -> G_fp8
    unsigned char*  Gf  = (unsigned char*)ws;                     // [L][L] fp8 64MB (overlays wT)
    unsigned short* wbf = wT + (size_t)L_DIM * P_DIM;             // [P][L] 64MB
    unsigned short* G   = wbf + (size_t)P_DIM * L_DIM;            // [L][L] bf16 128MB
    float* bv = (float*)(G + (size_t)L_DIM * L_DIM);              // [B][L] 8MB
    float* uv = bv + (size_t)B_DIM * L_DIM;                       // [B][L] 8MB
    unsigned short* a0 = (unsigned short*)(uv + (size_t)B_DIM * L_DIM);  // 4MB
    unsigned short* a1 = a0 + (size_t)B_DIM * L_DIM;              // 4MB
    unsigned short* xbf = a1 + (size_t)B_DIM * L_DIM;             // 2MB
    unsigned char* a0f = (unsigned char*)(xbf + (size_t)B_DIM * P_DIM); // 2MB
    unsigned char* a1f = a0f + (size_t)B_DIM * L_DIM;             // 2MB
    unsigned short* Ppart = (unsigned short*)(a1f + (size_t)B_DIM * L_DIM); // [8][B][L] bf16 32MB

    // casts
    cast_x_kernel<<<(B_DIM * P_DIM / 4 + 255) / 256, 256, 0, stream>>>(x, xbf, B_DIM * P_DIM);
    cast_transpose_w<<<dim3(L_DIM / 32, P_DIM / 32), dim3(32, 8), 0, stream>>>(w, wbf, wT);

    // gram: G = wT @ wT^T - I, symmetric upper triangle, 256^2 tiles (r10-proven, 341us)
    gemm_gram_sym<<<528, 512, 0, stream>>>(wT, G);

    // b = x @ w (needs wT; writes bv, uv, a0 bf16, a0f fp8)
    gemm_pipe<64, 128, 64, 2, 4, 1, B_DIM, L_DIM, P_DIM, 0><<<256, 512, 0, stream>>>(
        xbf, wT, bv, uv, a0, a0f);

    // quantize G -> fp8 (x64), k-shuffled; overlays wT (dead now)
    quantize_G<<<(int)(((size_t)L_DIM * L_DIM / 8) / 256), 256, 0, stream>>>(G, Gf);

    // scan steps: 42 fp8 (MX K=128, BM=256, split-K=8) + 6 exact-bf16 tail (split-K=4)
    unsigned short* ac = a0; unsigned short* an = a1;
    unsigned char* acf = a0f; unsigned char* anf = a1f;
    for (int it = 0; it < FP8_ITERS; ++it) {
        gemm_fp8<<<256, 512, 0, stream>>>(acf, Gf, Ppart);
        reduce_iter8<<<(B_DIM * L_DIM) / (256 * 8), 256, 0, stream>>>(Ppart, bv, uv, an, anf);
        unsigned short* t = ac; ac = an; an = t;
        unsigned char* tf = acf; acf = anf; anf = tf;
    }
    for (int it = 0; it < (NSTEPS - 2) - FP8_ITERS; ++it) {
        gemm2<128, 256, 2, 4, 4, L_DIM, 2048, 3><<<256, 512, 0, stream>>>(ac, G, Ppart);
        reduce_iter4<<<(B_DIM * L_DIM) / (256 * 8), 256, 0, stream>>>(Ppart, bv, uv, an, anf);
        unsigned short* t = ac; ac = an; an = t;
        unsigned char* tf = acf; acf = anf; anf = tf;
    }

    // recon = a_final @ w^T
    gemm_pipe<64, 64, 64, 2, 4, 3, B_DIM, P_DIM, L_DIM, 0><<<256, 512, 0, stream>>>(
        ac, wbf, out, nullptr, nullptr, nullptr);
}

// Round 19
// 2049.946 us; speedup vs baseline: 1.1445x; 1.1445x over previous
//
#include <hip/hip_runtime.h>
#include <stdint.h>
#include <math.h>

#define B_DIM 256
#define P_DIM 4096
#define L_DIM 8192
#define NSTEPS 50
#define STEP 0.1f
#define LAM 0.1f
#define FP8_ITERS 43          // scan steps in fp8; last 5 in exact bf16 (error-decay tail)
#define GSCALE 64.0f
#define ASCALE 16.0f
#define INV_SCALE (1.0f / (64.0f * 16.0f))

typedef __attribute__((ext_vector_type(8))) short bf16x8;
typedef __attribute__((ext_vector_type(4))) float f32x4;
typedef __attribute__((ext_vector_type(4))) int i32x4;
typedef __attribute__((ext_vector_type(8))) int i32x8;

__device__ __forceinline__ unsigned short f2bf(float f) {
    union { float f; uint32_t u; } x; x.f = f;
    uint32_t r = (x.u + 0x7FFF + ((x.u >> 16) & 1)) >> 16;
    return (unsigned short)r;
}
__device__ __forceinline__ float bf2f(unsigned short h) {
    union { uint32_t u; float f; } x; x.u = (uint32_t)h << 16; return x.f;
}

// k-shuffled fp8 layout (128-elem chunks): byte position of element k (r = k & 127):
//   dst = (k & ~127) + ((r>>6)&1)*64 + ((r>>3)&3)*16 + ((r>>5)&1)*8 + (k&7)
// Slot c (16B) holds a kk-pair; slots {g, 4+g} hold lane-group g's K=128 fragment.
// A and B share the packing -> hw (lane,byte)->k map is a common permutation -> exact dot.

// ---------------- cast x (f32 -> bf16), vectorized ----------------
__global__ void cast_x_kernel(const float* __restrict__ in, unsigned short* __restrict__ out, int n) {
    int i = (blockIdx.x * blockDim.x + threadIdx.x) * 4;
    if (i < n) {
        float4 v = *(const float4*)&in[i];
        ushort4 o;
        o.x = f2bf(v.x); o.y = f2bf(v.y); o.z = f2bf(v.z); o.w = f2bf(v.w);
        *(ushort4*)&out[i] = o;
    }
}

// ------------- cast + transpose w: w[P][L] f32 -> w_bf[P][L], wT_bf[L][P] -------------
__global__ void cast_transpose_w(const float* __restrict__ w,
                                 unsigned short* __restrict__ w_bf,
                                 unsigned short* __restrict__ wT_bf) {
    __shared__ float tile[32][33];
    int c0 = blockIdx.x * 32;
    int r0 = blockIdx.y * 32;
    int tx = threadIdx.x, ty = threadIdx.y;  // 32 x 8
#pragma unroll
    for (int i = ty; i < 32; i += 8) {
        float v = w[(size_t)(r0 + i) * L_DIM + c0 + tx];
        tile[i][tx] = v;
        w_bf[(size_t)(r0 + i) * L_DIM + c0 + tx] = f2bf(v);
    }
    __syncthreads();
#pragma unroll
    for (int i = ty; i < 32; i += 8) {
        wT_bf[(size_t)(c0 + i) * P_DIM + r0 + tx] = f2bf(tile[tx][i]);
    }
}

// ---------------- quantize G (bf16 -> fp8 e4m3 x64, k-shuffled) ----------------
__global__ void quantize_G(const unsigned short* __restrict__ G, unsigned char* __restrict__ Gf) {
    size_t i = ((size_t)blockIdx.x * 256 + threadIdx.x) * 8;
    bf16x8 v = *(const bf16x8*)&G[i];
    float f[8];
#pragma unroll
    for (int j = 0; j < 8; ++j) f[j] = bf2f((unsigned short)v[j]) * GSCALE;
    int q0 = __builtin_amdgcn_cvt_pk_fp8_f32(f[0], f[1], 0, false);
    q0 = __builtin_amdgcn_cvt_pk_fp8_f32(f[2], f[3], q0, true);
    int q1 = __builtin_amdgcn_cvt_pk_fp8_f32(f[4], f[5], 0, false);
    q1 = __builtin_amdgcn_cvt_pk_fp8_f32(f[6], f[7], q1, true);
    const int r = (int)(i & 127);
    size_t dst = (i & ~(size_t)127) + (size_t)((((r >> 6) & 1) << 6) + (((r >> 3) & 3) << 4) + (((r >> 5) & 1) << 3));
    *(int2*)(Gf + dst) = make_int2(q0, q1);
}

// ======================= gemm_pipe: NBUF=4 counted-vmcnt (b / recon) =======================
template <int BM, int BN, int BK, int WMC, int WNC, int EPI, int MM, int NN, int KK, int MAP>
__global__ __launch_bounds__(WMC * WNC * 64)
void gemm_pipe(const unsigned short* __restrict__ A,
               const unsigned short* __restrict__ Bt,
               float* __restrict__ Cf,
               float* __restrict__ uvec,
               unsigned short* __restrict__ aout,
               unsigned char* __restrict__ afp8) {
    constexpr int NWAVES = WMC * WNC;
    constexpr int WM = BM / WMC, WN = BN / WNC;
    constexpr int MF = WM / 16, NF = WN / 16;
    constexpr int ACH = BM / (8 * NWAVES);
    constexpr int BCH = BN / (8 * NWAVES);
    constexpr int LPS = ACH + BCH;
    constexpr int NT = KK / BK;
    static_assert(BK == 64, "swizzle hardcoded for BK=64");
    static_assert(ACH * 8 * NWAVES == BM && BCH * 8 * NWAVES == BN, "stage geometry");
    static_assert(NT % 4 == 0 && NT >= 8, "pipeline geometry");

    __shared__ __align__(16) unsigned short As[4][BM * BK];
    __shared__ __align__(16) unsigned short Bs[4][BN * BK];

    const int tid = threadIdx.x;
    const int w = tid >> 6;
    const int l = tid & 63;
    const int wr = w / WNC, wc = w % WNC;

    const int id = blockIdx.x;
    int bx, by;
    if constexpr (MAP == 0) {
        constexpr int PPX = (NN / BN) / 8;
        static_assert(MM / BM == 4 && (NN / BN) % 8 == 0, "panel map geometry");
        bx = (id & 7) * PPX + ((id >> 3) >> 2);
        by = (id >> 3) & 3;
    } else {
        constexpr int GY = MM / BM;
        by = id % GY;
        bx = id / GY;
    }
    const int row0 = by * BM;
    const int col0 = bx * BN;

    const int lrow = l >> 3;
    const int lcol = (((l & 7) ^ lrow) * 8);

    const unsigned short* gA = A + (size_t)(row0 + lrow) * KK + lcol;
    const unsigned short* gB = Bt + (size_t)(col0 + lrow) * KK + lcol;

    auto stage = [&](int buf, int k0) {
#pragma unroll
        for (int i = 0; i < ACH; ++i) {
            const int chunk = i * NWAVES + w;
            __builtin_amdgcn_global_load_lds(
                (const __attribute__((address_space(1))) void*)(gA + (size_t)chunk * 8 * KK + k0),
                (__attribute__((address_space(3))) void*)(&As[buf][chunk * 512]), 16, 0, 0);
        }
#pragma unroll
        for (int i = 0; i < BCH; ++i) {
            const int chunk = i * NWAVES + w;
            __builtin_amdgcn_global_load_lds(
                (const __attribute__((address_space(1))) void*)(gB + (size_t)chunk * 8 * KK + k0),
                (__attribute__((address_space(3))) void*)(&Bs[buf][chunk * 512]), 16, 0, 0);
        }
    };

    f32x4 acc[MF][NF] = {};

    auto compute = [&](int buf) {
#pragma unroll
        for (int kk = 0; kk < BK; kk += 32) {
            const int kslot = (kk >> 3) + (l >> 4);
            bf16x8 af[MF], bfr[NF];
#pragma unroll
            for (int mf = 0; mf < MF; ++mf) {
                const int arow = wr * WM + mf * 16 + (l & 15);
                af[mf] = *(const bf16x8*)&As[buf][arow * BK + ((kslot ^ (arow & 7)) << 3)];
            }
#pragma unroll
            for (int nf = 0; nf < NF; ++nf) {
                const int brow = wc * WN + nf * 16 + (l & 15);
                bfr[nf] = *(const bf16x8*)&Bs[buf][brow * BK + ((kslot ^ (brow & 7)) << 3)];
            }
#pragma unroll
            for (int mf = 0; mf < MF; ++mf)
#pragma unroll
                for (int nf = 0; nf < NF; ++nf)
                    acc[mf][nf] = __builtin_amdgcn_mfma_f32_16x16x32_bf16(
                        af[mf], bfr[nf], acc[mf][nf], 0, 0, 0);
        }
    };

#define PH(BUF, TT, WAITN, DOSTG)                                            \
    asm volatile("s_waitcnt vmcnt(%0)" ::"i"(WAITN) : "memory");             \
    __builtin_amdgcn_s_barrier();                                            \
    asm volatile("" ::: "memory");                                           \
    if (DOSTG) stage((BUF + 3) & 3, ((TT) + 3) * BK);                        \
    compute(BUF);

    stage(0, 0);
    stage(1, BK);
    stage(2, 2 * BK);
#pragma unroll 1
    for (int t = 0; t < NT - 4; t += 4) {
        PH(0, t + 0, 2 * LPS, true)
        PH(1, t + 1, 2 * LPS, true)
        PH(2, t + 2, 2 * LPS, true)
        PH(3, t + 3, 2 * LPS, true)
    }
    PH(0, NT - 4, 2 * LPS, true)
    PH(1, NT - 3, 2 * LPS, false)
    PH(2, NT - 2, LPS, false)
    PH(3, NT - 1, 0, false)
#undef PH

    const int er = (l >> 4) * 4;
    const int ec = l & 15;
#pragma unroll
    for (int mf = 0; mf < MF; ++mf) {
#pragma unroll
        for (int nf = 0; nf < NF; ++nf) {
#pragma unroll
            for (int j = 0; j < 4; ++j) {
                int gr = row0 + wr * WM + mf * 16 + er + j;
                int gc = col0 + wc * WN + nf * 16 + ec;
                size_t idx = (size_t)gr * NN + gc;
                float v = acc[mf][nf][j];
                if constexpr (EPI == 1) {
                    Cf[idx] = v;
                    float u0 = STEP * v;
                    uvec[idx] = u0;
                    float a = (u0 > LAM) ? (u0 - LAM) : 0.0f;
                    aout[idx] = f2bf(a);
                    float a16 = a * ASCALE;
                    int q = __builtin_amdgcn_cvt_pk_fp8_f32(a16, a16, 0, false);
                    const int r = gc & 127;
                    size_t fd = (size_t)gr * L_DIM + (size_t)(gc & ~127) +
                                (size_t)((((r >> 6) & 1) << 6) + (((r >> 3) & 3) << 4) + (((r >> 5) & 1) << 3) + (r & 7));
                    afp8[fd] = (unsigned char)(q & 0xff);
                } else {
                    Cf[idx] = v;
                }
            }
        }
    }
}

// ======================= gemm_gram_sym v1: 256^2 tiles, 8 waves, 528 blocks (r10-proven) ========
__global__ __launch_bounds__(512, 2)
void gemm_gram_sym(const unsigned short* __restrict__ A,
                   unsigned short* __restrict__ G) {
    constexpr int BM = 256, BN = 256, BK = 64;
    constexpr int WMC = 2, WNC = 4, NWAVES = 8;
    constexpr int WM = 128, WN = 64, MF = 8, NF = 4;
    constexpr int ACH = 4, BCH = 4, LPS = 8;
    constexpr int NT = P_DIM / BK;   // 64

    __shared__ __align__(16) unsigned short sh[4 * 256 * 64];  // 128 KB
#define ASB(buf) (sh + (buf) * (256 * 64))
#define BSB(buf) (sh + (2 + (buf)) * (256 * 64))

    const int tid = threadIdx.x;
    const int w = tid >> 6;
    const int l = tid & 63;
    const int wr = w / WNC, wc = w % WNC;

    const int id = blockIdx.x;
    const int i = (int)((65.0f - sqrtf(4225.0f - 8.0f * (float)id)) * 0.5f);
    const int cum = i * (65 - i) / 2;
    const int j = i + (id - cum);
    const int by = i, bx = j;
    const int row0 = by * BM;
    const int col0 = bx * BN;

    const int lrow = l >> 3;
    const int lcol = (((l & 7) ^ lrow) * 8);

    const unsigned short* gA = A + (size_t)(row0 + lrow) * P_DIM + lcol;
    const unsigned short* gB = A + (size_t)(col0 + lrow) * P_DIM + lcol;

    auto stage = [&](int buf, int t) {
        const int k0 = t * BK;
#pragma unroll
        for (int c = 0; c < ACH; ++c) {
            const int chunk = c * NWAVES + w;
            __builtin_amdgcn_global_load_lds(
                (const __attribute__((address_space(1))) void*)(gA + (size_t)chunk * 8 * P_DIM + k0),
                (__attribute__((address_space(3))) void*)(ASB(buf) + chunk * 512), 16, 0, 0);
        }
#pragma unroll
        for (int c = 0; c < BCH; ++c) {
            const int chunk = c * NWAVES + w;
            __builtin_amdgcn_global_load_lds(
                (const __attribute__((address_space(1))) void*)(gB + (size_t)chunk * 8 * P_DIM + k0),
                (__attribute__((address_space(3))) void*)(BSB(buf) + chunk * 512), 16, 0, 0);
        }
    };

    f32x4 acc[MF][NF] = {};

    auto compute = [&](int buf) {
#pragma unroll
        for (int kk = 0; kk < BK; kk += 32) {
            const int kslot = (kk >> 3) + (l >> 4);
            bf16x8 af[MF], bfr[NF];
#pragma unroll
            for (int mf = 0; mf < MF; ++mf) {
                const int arow = wr * WM + mf * 16 + (l & 15);
                af[mf] = *(const bf16x8*)&ASB(buf)[arow * BK + ((kslot ^ (arow & 7)) << 3)];
            }
#pragma unroll
            for (int nf = 0; nf < NF; ++nf) {
                const int brow = wc * WN + nf * 16 + (l & 15);
                bfr[nf] = *(const bf16x8*)&BSB(buf)[brow * BK + ((kslot ^ (brow & 7)) << 3)];
            }
#pragma unroll
            for (int mf = 0; mf < MF; ++mf)
#pragma unroll
                for (int nf = 0; nf < NF; ++nf)
                    acc[mf][nf] = __builtin_amdgcn_mfma_f32_16x16x32_bf16(
                        af[mf], bfr[nf], acc[mf][nf], 0, 0, 0);
        }
    };

#define PH2(BUF, WAITN, DOSTG, TT)                                           \
    asm volatile("s_waitcnt vmcnt(%0)" ::"i"(WAITN) : "memory");             \
    __builtin_amdgcn_s_barrier();                                            \
    asm volatile("" ::: "memory");                                           \
    compute(BUF);                                                            \
    __builtin_amdgcn_s_barrier();                                            \
    asm volatile("" ::: "memory");                                           \
    if (DOSTG) stage(BUF, (TT) + 2);

    stage(0, 0);
    stage(1, 1);
#pragma unroll 1
    for (int t = 0; t < NT - 2; t += 2) {
        PH2(0, LPS, true, t)
        PH2(1, LPS, true, t + 1)
    }
    PH2(0, LPS, false, 0)
    PH2(1, 0, false, 0)
#undef PH2

    const int er = (l >> 4) * 4;
    const int ec = l & 15;

#pragma unroll
    for (int mf = 0; mf < MF; ++mf)
#pragma unroll
        for (int nf = 0; nf < NF; ++nf)
#pragma unroll
            for (int jj = 0; jj < 4; ++jj) {
                int gr = row0 + wr * WM + mf * 16 + er + jj;
                int gc = col0 + wc * WN + nf * 16 + ec;
                float v = acc[mf][nf][jj];
                if (gr == gc) v -= 1.0f;
                G[(size_t)gr * L_DIM + gc] = f2bf(v);
            }

    if (by != bx) {
        unsigned short* T = sh;
#pragma unroll 1
        for (int p = 0; p < 2; ++p) {
            __syncthreads();
            if ((wc >> 1) == p) {
#pragma unroll
                for (int mf = 0; mf < MF; ++mf)
#pragma unroll
                    for (int nf = 0; nf < NF; ++nf)
#pragma unroll
                        for (int jj = 0; jj < 4; ++jj) {
                            const int gr_l = wr * WM + mf * 16 + er + jj;
                            const int gc_l = (wc & 1) * 64 + nf * 16 + ec;
                            T[gc_l * 256 + (gr_l ^ ((gc_l & 7) << 2))] = f2bf(acc[mf][nf][jj]);
                        }
            }
            __syncthreads();
            const int rr = tid >> 6;
            const int cc = (tid & 63) * 4;
#pragma unroll
            for (int s = 0; s < 16; ++s) {
                const int r = s * 8 + rr;
                uint2 val = *(const uint2*)&T[r * 256 + (cc ^ ((r & 7) << 2))];
                *(uint2*)&G[(size_t)(col0 + p * 128 + r) * L_DIM + row0 + cc] = val;
            }
        }
    }
#undef ASB
#undef BSB
}

// ======================= gemm2: bf16 NBUF=2 two-barrier counted-vmcnt (bf16-tail iters) =====
template <int BM, int BN, int WMC, int WNC, int EPI, int KROW, int KLOOP, int MAP>
__global__ __launch_bounds__(WMC * WNC * 64, 2)
void gemm2(const unsigned short* __restrict__ A,
           const unsigned short* __restrict__ Bt,
           unsigned short* __restrict__ Obf) {
    constexpr int NWAVES = WMC * WNC;
    constexpr int WM = BM / WMC, WN = BN / WNC;
    constexpr int MF = WM / 16, NF = WN / 16;
    constexpr int ACH = BM / (8 * NWAVES);
    constexpr int BCH = BN / (8 * NWAVES);
    constexpr int LPS = ACH + BCH;
    constexpr int BK = 64;
    constexpr int NT = KLOOP / BK;
    static_assert(ACH * 8 * NWAVES == BM && BCH * 8 * NWAVES == BN, "stage geometry");
    static_assert(NT % 2 == 0 && NT >= 4, "pipeline geometry");

    __shared__ __align__(16) unsigned short As[2][BM * BK];
    __shared__ __align__(16) unsigned short Bs[2][BN * BK];

    const int tid = threadIdx.x;
    const int w = tid >> 6;
    const int l = tid & 63;
    const int wr = w / WNC, wc = w % WNC;

    const int id = blockIdx.x;
    int bx, by, koff;
    size_t o_off;
    {
        const int xcd = id & 7;
        by = (id >> 3) & 1;
        const int pp = id >> 4;
        const int slice = pp & 3;
        bx = xcd * 4 + (pp >> 2);
        koff = slice * KLOOP;
        o_off = (size_t)slice * B_DIM * L_DIM;
    }
    const int row0 = by * BM;
    const int col0 = bx * BN;

    const int lrow = l >> 3;
    const int lcol = (((l & 7) ^ lrow) * 8);

    const unsigned short* gA = A + (size_t)(row0 + lrow) * KROW + koff + lcol;
    const unsigned short* gB = Bt + (size_t)(col0 + lrow) * KROW + koff + lcol;

    auto stage = [&](int buf, int t) {
        const int k0 = t * BK;
#pragma unroll
        for (int i = 0; i < ACH; ++i) {
            const int chunk = i * NWAVES + w;
            __builtin_amdgcn_global_load_lds(
                (const __attribute__((address_space(1))) void*)(gA + (size_t)chunk * 8 * KROW + k0),
                (__attribute__((address_space(3))) void*)(&As[buf][chunk * 512]), 16, 0, 0);
        }
#pragma unroll
        for (int i = 0; i < BCH; ++i) {
            const int chunk = i * NWAVES + w;
            __builtin_amdgcn_global_load_lds(
                (const __attribute__((address_space(1))) void*)(gB + (size_t)chunk * 8 * KROW + k0),
                (__attribute__((address_space(3))) void*)(&Bs[buf][chunk * 512]), 16, 0, 0);
        }
    };

    f32x4 acc[MF][NF] = {};

    auto compute = [&](int buf) {
#pragma unroll
        for (int kk = 0; kk < BK; kk += 32) {
            const int kslot = (kk >> 3) + (l >> 4);
            bf16x8 af[MF], bfr[NF];
#pragma unroll
            for (int mf = 0; mf < MF; ++mf) {
                const int arow = wr * WM + mf * 16 + (l & 15);
                af[mf] = *(const bf16x8*)&As[buf][arow * BK + ((kslot ^ (arow & 7)) << 3)];
            }
#pragma unroll
            for (int nf = 0; nf < NF; ++nf) {
                const int brow = wc * WN + nf * 16 + (l & 15);
                bfr[nf] = *(const bf16x8*)&Bs[buf][brow * BK + ((kslot ^ (brow & 7)) << 3)];
            }
#pragma unroll
            for (int mf = 0; mf < MF; ++mf)
#pragma unroll
                for (int nf = 0; nf < NF; ++nf)
                    acc[mf][nf] = __builtin_amdgcn_mfma_f32_16x16x32_bf16(
                        af[mf], bfr[nf], acc[mf][nf], 0, 0, 0);
        }
    };

#define PH2(BUF, WAITN, DOSTG, TT)                                           \
    asm volatile("s_waitcnt vmcnt(%0)" ::"i"(WAITN) : "memory");             \
    __builtin_amdgcn_s_barrier();                                            \
    asm volatile("" ::: "memory");                                           \
    compute(BUF);                                                            \
    __builtin_amdgcn_s_barrier();                                            \
    asm volatile("" ::: "memory");                                           \
    if (DOSTG) stage(BUF, (TT) + 2);

    stage(0, 0);
    stage(1, 1);
#pragma unroll 1
    for (int t = 0; t < NT - 2; t += 2) {
        PH2(0, LPS, true, t)
        PH2(1, LPS, true, t + 1)
    }
    PH2(0, LPS, false, 0)
    PH2(1, 0, false, 0)
#undef PH2

    const int er = (l >> 4) * 4;
    const int ec = l & 15;
#pragma unroll
    for (int mf = 0; mf < MF; ++mf)
#pragma unroll
        for (int nf = 0; nf < NF; ++nf)
#pragma unroll
            for (int j = 0; j < 4; ++j) {
                int gr = row0 + wr * WM + mf * 16 + er + j;
                int gc = col0 + wc * WN + nf * 16 + ec;
                Obf[o_off + (size_t)gr * L_DIM + gc] = f2bf(acc[mf][nf][j]);
            }
}

// ======================= gemm_fp8: iter GEMM, MX K=128 MFMA (scaled intrinsic, r17-proven) ======
// __builtin_amdgcn_mfma_scale_f32_16x16x128_f8f6f4, cbsz=blgp=0 (e4m3/e4m3),
// scale = 127 (e8m0 encoding of 2^0 = 1.0) -> products identical to non-scaled fp8.
// A and B share the k-shuffled packing -> hw (lane,byte)->k map is a common permutation
// of both operands -> correct dot product; only f32 summation order differs (~1 ulp).
template <int BM, int BN, int WMC, int WNC>
__global__ __launch_bounds__(WMC * WNC * 64, 2)
void gemm_fp8(const unsigned char* __restrict__ A,
              const unsigned char* __restrict__ Bt,
              unsigned short* __restrict__ Obf) {
    constexpr int NWAVES = WMC * WNC;              // 8
    constexpr int WM = BM / WMC, WN = BN / WNC;    // 64, 64
    constexpr int MF = WM / 16, NF = WN / 16;      // 4, 4
    constexpr int BKB = 128;
    constexpr int ACH = BM / (8 * NWAVES);         // 2
    constexpr int BCH = BN / (8 * NWAVES);         // 4
    constexpr int LPS = ACH + BCH;                 // 6
    constexpr int KLOOP = 2048;
    constexpr int NT = KLOOP / BKB;                // 16
    constexpr int KKB = L_DIM;
    static_assert(ACH * 8 * NWAVES == BM && BCH * 8 * NWAVES == BN, "stage geometry");

    __shared__ __align__(16) unsigned char As[2][BM * BKB];   // 32 KB
    __shared__ __align__(16) unsigned char Bs[2][BN * BKB];   // 64 KB

    const int tid = threadIdx.x;
    const int w = tid >> 6;
    const int l = tid & 63;
    const int wr = w / WNC, wc = w % WNC;

    const int id = blockIdx.x;
    const int xcd = id & 7;
    const int by = (id >> 3) & 1;
    const int pp = id >> 4;
    const int slice = pp & 3;
    const int bx = xcd * 4 + (pp >> 2);
    const int row0 = by * BM;
    const int col0 = bx * BN;
    const int koff = slice * KLOOP;

    const int lrow = l >> 3;
    const int lcol = (((l & 7) ^ lrow) << 4);

    const unsigned char* gA = A + (size_t)(row0 + lrow) * KKB + koff + lcol;
    const unsigned char* gB = Bt + (size_t)(col0 + lrow) * KKB + koff + lcol;

    auto stage = [&](int buf, int t) {
        const int k0 = t * BKB;
#pragma unroll
        for (int i = 0; i < ACH; ++i) {
            const int chunk = i * NWAVES + w;
            __builtin_amdgcn_global_load_lds(
                (const __attribute__((address_space(1))) void*)(gA + (size_t)chunk * 8 * KKB + k0),
                (__attribute__((address_space(3))) void*)(&As[buf][chunk * 1024]), 16, 0, 0);
        }
#pragma unroll
        for (int i = 0; i < BCH; ++i) {
            const int chunk = i * NWAVES + w;
            __builtin_amdgcn_global_load_lds(
                (const __attribute__((address_space(1))) void*)(gB + (size_t)chunk * 8 * KKB + k0),
                (__attribute__((address_space(3))) void*)(&Bs[buf][chunk * 1024]), 16, 0, 0);
        }
    };

    f32x4 acc[MF][NF] = {};

    auto compute = [&](int buf) {
        const int g = l >> 4;
        i32x8 a8[MF], b8[NF];
#pragma unroll
        for (int mf = 0; mf < MF; ++mf) {
            const int arow = wr * WM + mf * 16 + (l & 15);
            i32x4 lo = *(const i32x4*)&As[buf][arow * BKB + (((g) ^ (arow & 7)) << 4)];
            i32x4 hi = *(const i32x4*)&As[buf][arow * BKB + (((4 + g) ^ (arow & 7)) << 4)];
            a8[mf] = i32x8{lo[0], lo[1], lo[2], lo[3], hi[0], hi[1], hi[2], hi[3]};
        }
#pragma unroll
        for (int nf = 0; nf < NF; ++nf) {
            const int brow = wc * WN + nf * 16 + (l & 15);
            i32x4 lo = *(const i32x4*)&Bs[buf][brow * BKB + (((g) ^ (brow & 7)) << 4)];
            i32x4 hi = *(const i32x4*)&Bs[buf][brow * BKB + (((4 + g) ^ (brow & 7)) << 4)];
            b8[nf] = i32x8{lo[0], lo[1], lo[2], lo[3], hi[0], hi[1], hi[2], hi[3]};
        }
#pragma unroll
        for (int mf = 0; mf < MF; ++mf)
#pragma unroll
            for (int nf = 0; nf < NF; ++nf)
                acc[mf][nf] = __builtin_amdgcn_mfma_scale_f32_16x16x128_f8f6f4(
                    a8[mf], b8[nf], acc[mf][nf],
                    0, 0,        // cbsz, blgp: FMT = fp8 e4m3 for A and B
                    0, 127,      // scale_a sel, scale_a = e8m0(2^0) = 1.0
                    0, 127);     // scale_b sel, scale_b = 1.0
    };

#define PH2(BUF, WAITN, DOSTG, TT)                                           \
    asm volatile("s_waitcnt vmcnt(%0)" ::"i"(WAITN) : "memory");             \
    __builtin_amdgcn_s_barrier();                                            \
    asm volatile("" ::: "memory");                                           \
    compute(BUF);                                                            \
    __builtin_amdgcn_s_barrier();                                            \
    asm volatile("" ::: "memory");                                           \
    if (DOSTG) stage(BUF, (TT) + 2);

    stage(0, 0);
    stage(1, 1);
#pragma unroll 1
    for (int t = 0; t < NT - 2; t += 2) {
        PH2(0, LPS, true, t)
        PH2(1, LPS, true, t + 1)
    }
    PH2(0, LPS, false, 0)
    PH2(1, 0, false, 0)
#undef PH2

    const int er = (l >> 4) * 4;
    const int ec = l & 15;
    const size_t o_off = (size_t)slice * B_DIM * L_DIM;
#pragma unroll
    for (int mf = 0; mf < MF; ++mf)
#pragma unroll
        for (int nf = 0; nf < NF; ++nf)
#pragma unroll
            for (int j = 0; j < 4; ++j) {
                int gr = row0 + wr * WM + mf * 16 + er + j;
                int gc = col0 + wc * WN + nf * 16 + ec;
                Obf[o_off + (size_t)gr * L_DIM + gc] = f2bf(acc[mf][nf][j] * INV_SCALE);
            }
}

// ---------------- reduce: u' = 0.9u + 0.1b - 0.1*sum(partials); a' = thr(u') (bf16 + fp8) ------
__global__ void reduce_iter(const unsigned short* __restrict__ P,
                            const float* __restrict__ bv,
                            float* __restrict__ uv,
                            unsigned short* __restrict__ an,
                            unsigned char* __restrict__ anf) {
    constexpr size_t SL = (size_t)B_DIM * L_DIM;
    size_t i = ((size_t)blockIdx.x * 256 + threadIdx.x) * 8;
    float s[8] = {};
#pragma unroll
    for (int sl = 0; sl < 4; ++sl) {
        ushort4 p0 = *(const ushort4*)&P[sl * SL + i];
        ushort4 p1 = *(const ushort4*)&P[sl * SL + i + 4];
        s[0] += bf2f(p0.x); s[1] += bf2f(p0.y); s[2] += bf2f(p0.z); s[3] += bf2f(p0.w);
        s[4] += bf2f(p1.x); s[5] += bf2f(p1.y); s[6] += bf2f(p1.z); s[7] += bf2f(p1.w);
    }
    float4 b0 = *(const float4*)&bv[i];
    float4 b1 = *(const float4*)&bv[i + 4];
    float4 u0 = *(const float4*)&uv[i];
    float4 u1 = *(const float4*)&uv[i + 4];
    float un[8];
    un[0] = 0.9f * u0.x + STEP * b0.x - STEP * s[0];
    un[1] = 0.9f * u0.y + STEP * b0.y - STEP * s[1];
    un[2] = 0.9f * u0.z + STEP * b0.z - STEP * s[2];
    un[3] = 0.9f * u0.w + STEP * b0.w - STEP * s[3];
    un[4] = 0.9f * u1.x + STEP * b1.x - STEP * s[4];
    un[5] = 0.9f * u1.y + STEP * b1.y - STEP * s[5];
    un[6] = 0.9f * u1.z + STEP * b1.z - STEP * s[6];
    un[7] = 0.9f * u1.w + STEP * b1.w - STEP * s[7];
    *(float4*)&uv[i] = make_float4(un[0], un[1], un[2], un[3]);
    *(float4*)&uv[i + 4] = make_float4(un[4], un[5], un[6], un[7]);
    float a[8];
#pragma unroll
    for (int j = 0; j < 8; ++j) a[j] = (un[j] > LAM) ? (un[j] - LAM) : 0.0f;
    ushort4 o0, o1;
    o0.x = f2bf(a[0]); o0.y = f2bf(a[1]); o0.z = f2bf(a[2]); o0.w = f2bf(a[3]);
    o1.x = f2bf(a[4]); o1.y = f2bf(a[5]); o1.z = f2bf(a[6]); o1.w = f2bf(a[7]);
    *(ushort4*)&an[i] = o0;
    *(ushort4*)&an[i + 4] = o1;
    int q0 = __builtin_amdgcn_cvt_pk_fp8_f32(a[0] * ASCALE, a[1] * ASCALE, 0, false);
    q0 = __builtin_amdgcn_cvt_pk_fp8_f32(a[2] * ASCALE, a[3] * ASCALE, q0, true);
    int q1 = __builtin_amdgcn_cvt_pk_fp8_f32(a[4] * ASCALE, a[5] * ASCALE, 0, false);
    q1 = __builtin_amdgcn_cvt_pk_fp8_f32(a[6] * ASCALE, a[7] * ASCALE, q1, true);
    const int r = (int)(i & 127);
    size_t dst = (i & ~(size_t)127) + (size_t)((((r >> 6) & 1) << 6) + (((r >> 3) & 3) << 4) + (((r >> 5) & 1) << 3));
    *(int2*)(anf + dst) = make_int2(q0, q1);
}

extern "C" void kernel_launch(void* const* d_in, const int* in_sizes, int n_in,
                              void* d_out, int out_size, void* d_ws, size_t ws_size,
                              hipStream_t stream) {
    (void)in_sizes; (void)n_in; (void)out_size; (void)ws_size;
    const float* x = (const float*)d_in[0];
    const float* w = (const float*)d_in[1];
    float* out = (float*)d_out;

    char* ws = (char*)d_ws;
    unsigned short* wT  = (unsigned short*)ws;                    // [L][P] 64MB; dead after b -> G_fp8
    unsigned char*  Gf  = (unsigned char*)ws;                     // [L][L] fp8 64MB (overlays wT)
    unsigned short* wbf = wT + (size_t)L_DIM * P_DIM;             // [P][L] 64MB
    unsigned short* G   = wbf + (size_t)P_DIM * L_DIM;            // [L][L] bf16 128MB
    float* bv = (float*)(G + (size_t)L_DIM * L_DIM);              // [B][L] 8MB
    float* uv = bv + (size_t)B_DIM * L_DIM;                       // [B][L] 8MB
    unsigned short* a0 = (unsigned short*)(uv + (size_t)B_DIM * L_DIM);  // 4MB
    unsigned short* a1 = a0 + (size_t)B_DIM * L_DIM;              // 4MB
    unsigned short* xbf = a1 + (size_t)B_DIM * L_DIM;             // 2MB
    unsigned char* a0f = (unsigned char*)(xbf + (size_t)B_DIM * P_DIM); // 2MB
    unsigned char* a1f = a0f + (size_t)B_DIM * L_DIM;             // 2MB
    unsigned short* Ppart = (unsigned short*)(a1f + (size_t)B_DIM * L_DIM); // [4][B][L] bf16 16MB

    // casts
    cast_x_kernel<<<(B_DIM * P_DIM / 4 + 255) / 256, 256, 0, stream>>>(x, xbf, B_DIM * P_DIM);
    cast_transpose_w<<<dim3(L_DIM / 32, P_DIM / 32), dim3(32, 8), 0, stream>>>(w, wbf, wT);

    // gram: G = wT @ wT^T - I, symmetric upper triangle, 256^2 tiles (r10-proven, 341us)
    gemm_gram_sym<<<528, 512, 0, stream>>>(wT, G);

    // b = x @ w (needs wT; writes bv, uv, a0 bf16, a0f fp8)
    gemm_pipe<64, 128, 64, 2, 4, 1, B_DIM, L_DIM, P_DIM, 0><<<256, 512, 0, stream>>>(
        xbf, wT, bv, uv, a0, a0f);

    // quantize G -> fp8 (x64), k-shuffled; overlays wT (dead now)
    quantize_G<<<(int)(((size_t)L_DIM * L_DIM / 8) / 256), 256, 0, stream>>>(G, Gf);

    // scan steps: 43 fp8 (MX K=128 MFMA) + 5 exact-bf16 tail
    unsigned short* ac = a0; unsigned short* an = a1;
    unsigned char* acf = a0f; unsigned char* anf = a1f;
    for (int it = 0; it < FP8_ITERS; ++it) {
        gemm_fp8<128, 256, 2, 4><<<256, 512, 0, stream>>>(acf, Gf, Ppart);
        reduce_iter<<<(B_DIM * L_DIM) / (256 * 8), 256, 0, stream>>>(Ppart, bv, uv, an, anf);
        unsigned short* t = ac; ac = an; an = t;
        unsigned char* tf = acf; acf = anf; anf = tf;
    }
    for (int it = 0; it < (NSTEPS - 2) - FP8_ITERS; ++it) {
        gemm2<128, 256, 2, 4, 4, L_DIM, 2048, 3><<<256, 512, 0, stream>>>(ac, G, Ppart);
        reduce_iter<<<(B_DIM * L_DIM) / (256 * 8), 256, 0, stream>>>(Ppart, bv, uv, an, anf);
        unsigned short* t = ac; ac = an; an = t;
        unsigned char* tf = acf; acf = anf; anf = tf;
    }

    // recon = a_final @ w^T
    gemm_pipe<64, 64, 64, 2, 4, 3, B_DIM, P_DIM, L_DIM, 0><<<256, 512, 0, stream>>>(
        ac, wbf, out, nullptr, nullptr, nullptr);
}